// Round 9
// baseline (373.390 us; speedup 1.0000x reference)
//
#include <hip/hip_runtime.h>
#include <stdint.h>

#define NB 16
#define LQ 2048
#define LK 2048
#define DH 64
#define QT 16
#define NSTRIP 32            // strips of 16 keys per wave; 4 waves x 32 x 16 = 2048

typedef short bf16x8 __attribute__((ext_vector_type(8)));
typedef short bf16x4 __attribute__((ext_vector_type(4)));
typedef float f32x4 __attribute__((ext_vector_type(4)));

__device__ __forceinline__ unsigned short f2bf(float f) {
    union { float f; uint32_t u; } v; v.f = f;
    uint32_t u = v.u;
    u += 0x7FFFu + ((u >> 16) & 1u);   // RNE; inputs finite/bounded
    return (unsigned short)(u >> 16);
}
__device__ __forceinline__ float bf2f(unsigned short h) {
    union { uint32_t u; float f; } v; v.u = ((uint32_t)h) << 16;
    return v.f;
}
__device__ __forceinline__ uint32_t pack2(float lo, float hi) {
    return (uint32_t)f2bf(lo) | ((uint32_t)f2bf(hi) << 16);
}

// ---------------- pre-pass: f32 -> bf16 (Q, K) and f32 -> bf16 transposed (V) ----
__global__ void convert_kernel(const float* __restrict__ q, const float* __restrict__ k,
                               const float* __restrict__ v,
                               unsigned short* __restrict__ qb,
                               unsigned short* __restrict__ kb,
                               unsigned short* __restrict__ vtb) {
    int bid = blockIdx.x;
    int tid = threadIdx.x;
    if (bid < 2048) {
        const float* src = (bid < 1024) ? q : k;
        unsigned short* dst = (bid < 1024) ? qb : kb;
        int64_t off = (int64_t)(bid & 1023) * 2048 + (int64_t)tid * 8;
        float4 a = *(const float4*)(src + off);
        float4 b4 = *(const float4*)(src + off + 4);
        uint4 o;
        o.x = pack2(a.x, a.y);
        o.y = pack2(a.z, a.w);
        o.z = pack2(b4.x, b4.y);
        o.w = pack2(b4.z, b4.w);
        *(uint4*)(dst + off) = o;
    } else {
        __shared__ unsigned short tile[64][72];
        int bid2 = bid - 2048;
        int bb = bid2 >> 5, kt = bid2 & 31;
        int k0 = kt * 64;
        int krow = tid >> 2, dc = (tid & 3) * 16;
        const float* vp = v + ((int64_t)(bb * LK) + k0 + krow) * DH + dc;
        float4 x0 = *(const float4*)(vp);
        float4 x1 = *(const float4*)(vp + 4);
        float4 x2 = *(const float4*)(vp + 8);
        float4 x3 = *(const float4*)(vp + 12);
        float vals[16] = {x0.x, x0.y, x0.z, x0.w, x1.x, x1.y, x1.z, x1.w,
                          x2.x, x2.y, x2.z, x2.w, x3.x, x3.y, x3.z, x3.w};
        #pragma unroll
        for (int i = 0; i < 16; ++i) tile[dc + i][krow] = f2bf(vals[i]);
        __syncthreads();
        int d = tid >> 2, kc = (tid & 3) * 16;
        uint4 r0 = *(const uint4*)&tile[d][kc];
        uint4 r1 = *(const uint4*)&tile[d][kc + 8];
        unsigned short* op = vtb + ((int64_t)(bb * DH) + d) * LK + k0 + kc;
        *(uint4*)op = r0;
        *(uint4*)(op + 8) = r1;
    }
}

// asm load helpers (issue order preserved between volatile asms)
__device__ __forceinline__ void ld_f32x4(f32x4& d, const float* p) {
    asm volatile("global_load_dwordx4 %0, %1, off" : "=v"(d) : "v"((uint64_t)p));
}
__device__ __forceinline__ void ld_bf16x8(bf16x8& d, const unsigned short* p) {
    asm volatile("global_load_dwordx4 %0, %1, off" : "=v"(d) : "v"((uint64_t)p));
}

__device__ __forceinline__ f32x4 pv_mfma(bf16x4 a, bf16x4 bfrag, f32x4 c) {
#if defined(__has_builtin)
#if __has_builtin(__builtin_amdgcn_mfma_f32_16x16x16bf16_1k)
    return __builtin_amdgcn_mfma_f32_16x16x16bf16_1k(a, bfrag, c, 0, 0, 0);
#else
    asm("v_mfma_f32_16x16x16_bf16 %0, %1, %2, %0" : "+v"(c) : "v"(a), "v"(bfrag));
    return c;
#endif
#else
    asm("v_mfma_f32_16x16x16_bf16 %0, %1, %2, %0" : "+v"(c) : "v"(a), "v"(bfrag));
    return c;
#endif
}

// ---------------- fused attention, e-in-registers, LDS-free data path ------------
// grid 2048 (16 b x 128 q-tiles), 256 threads (4 waves), QT=16 rows/block.
// Each wave owns 32 strips of 16 keys (512 keys). e never leaves registers:
// S^T lane layout (keys lg*4+j of q-row lr) IS the 16x16x16 PV A-fragment.
__launch_bounds__(256, 4)
__global__ void attn_kernel(const unsigned short* __restrict__ qb,
                            const unsigned short* __restrict__ kb,
                            const unsigned short* __restrict__ vtb,
                            const float* __restrict__ mask,
                            float* __restrict__ out, float* __restrict__ attn) {
    __shared__ float den_part[4][16];
    __shared__ float pp[3][4][16][16];   // [wave-1][dimtile][row][col]

    int bid = blockIdx.x;
    int swz = (bid & 7) * 256 + (bid >> 3);   // bijective XCD swizzle (2048 % 8 == 0)
    int b = swz >> 7;
    int q0 = (swz & 127) * QT;

    int tid = threadIdx.x;
    int lane = tid & 63;
    int wave = tid >> 6;                 // 0..3 : key range [wave*512, wave*512+512)
    int lr = lane & 15, lg = lane >> 4;

    // Q fragments (B-operand of S^T = K·Q^T): lane holds Q[q0+lr][8*lg+i]
    bf16x8 qf0, qf1;
    {
        const unsigned short* qp = qb + ((int64_t)(b * LQ + q0 + lr)) * DH + 8 * lg;
        qf0 = *(const bf16x8*)qp;
        qf1 = *(const bf16x8*)(qp + 32);
    }

    const unsigned short* kpw =
        kb + (int64_t)b * LK * DH + (wave * NSTRIP * 16 + lr) * DH + 8 * lg;
    const float* mrow =
        mask + ((int64_t)(b * LQ + q0 + lr)) * LK + wave * NSTRIP * 16 + lg * 4;

    uint32_t es[2 * NSTRIP];             // packed bf16 e, 2 words per strip
    float dsum = 0.f;

    // ---- phase 1: stream mask(HBM)+K(L2) through a 3-deep asm ring; S^T MFMA,
    //      exp, mask-select; e stays in registers. Counted vmcnt, never early-0.
    {
        f32x4  mk[3];
        bf16x8 ka[3], kb_[3];
        #pragma unroll
        for (int t = 0; t < 3; ++t) {
            ld_f32x4(mk[t], mrow + t * 16);
            ld_bf16x8(ka[t],  kpw + (int64_t)t * 16 * DH);
            ld_bf16x8(kb_[t], kpw + (int64_t)t * 16 * DH + 32);
        }
        #pragma unroll
        for (int kt = 0; kt < NSTRIP; ++kt) {
            int s = kt % 3;
            if (kt < NSTRIP - 2)
                asm volatile("s_waitcnt vmcnt(6)"
                             : "+v"(mk[s]), "+v"(ka[s]), "+v"(kb_[s]));
            else if (kt == NSTRIP - 2)
                asm volatile("s_waitcnt vmcnt(3)"
                             : "+v"(mk[s]), "+v"(ka[s]), "+v"(kb_[s]));
            else
                asm volatile("s_waitcnt vmcnt(0)"
                             : "+v"(mk[s]), "+v"(ka[s]), "+v"(kb_[s]));
            __builtin_amdgcn_sched_barrier(0);

            f32x4 acc = {0.f, 0.f, 0.f, 0.f};
            acc = __builtin_amdgcn_mfma_f32_16x16x32_bf16(ka[s],  qf0, acc, 0, 0, 0);
            acc = __builtin_amdgcn_mfma_f32_16x16x32_bf16(kb_[s], qf1, acc, 0, 0, 0);
            // C[row=lg*4+j][col=lr] = S[q=lr][key = (wave*32+kt)*16 + lg*4 + j]
            unsigned short eb[4];
            #pragma unroll
            for (int j = 0; j < 4; ++j) {
                float sc = acc[j] * 0.125f;
                sc = fminf(fmaxf(sc, -15.0f), 15.0f);
                unsigned short p = f2bf(__expf(sc));
                eb[j] = (mk[s][j] != 0.f) ? p : (unsigned short)0;
                dsum += bf2f(eb[j]);
            }
            es[2 * kt]     = (uint32_t)eb[0] | ((uint32_t)eb[1] << 16);
            es[2 * kt + 1] = (uint32_t)eb[2] | ((uint32_t)eb[3] << 16);

            if (kt < NSTRIP - 3) {
                ld_f32x4(mk[s], mrow + (kt + 3) * 16);
                ld_bf16x8(ka[s],  kpw + (int64_t)(kt + 3) * 16 * DH);
                ld_bf16x8(kb_[s], kpw + (int64_t)(kt + 3) * 16 * DH + 32);
            }
        }
    }

    // per-row denominator partials (reduce over lg within wave)
    dsum += __shfl_xor(dsum, 16);
    dsum += __shfl_xor(dsum, 32);
    if (lane < 16) den_part[wave][lane] = dsum;
    __syncthreads();

    float inv;   // 1/den for q-row lr (the row this lane writes in attn)
    {
        float den = den_part[0][lr] + den_part[1][lr] + den_part[2][lr] +
                    den_part[3][lr] + 1e-6f;
        inv = 1.0f / den;
    }

    // ---- phase 2: per strip, attn write (from regs) interleaved with PV MFMA ----
    f32x4 pacc0 = {0.f, 0.f, 0.f, 0.f};
    f32x4 pacc1 = {0.f, 0.f, 0.f, 0.f};
    f32x4 pacc2 = {0.f, 0.f, 0.f, 0.f};
    f32x4 pacc3 = {0.f, 0.f, 0.f, 0.f};
    {
        float* arow = attn + ((int64_t)(b * LQ + q0 + lr)) * LK +
                      wave * NSTRIP * 16 + lg * 4;
        const unsigned short* vb =
            vtb + (int64_t)b * DH * LK + lr * LK + wave * NSTRIP * 16 + lg * 4;
        #pragma unroll
        for (int kt = 0; kt < NSTRIP; ++kt) {
            uint32_t w0 = es[2 * kt], w1 = es[2 * kt + 1];
            union { uint32_t u[2]; bf16x4 v; } eu;
            eu.u[0] = w0; eu.u[1] = w1;
            f32x4 ao;
            ao[0] = bf2f((unsigned short)(w0 & 0xffff)) * inv;
            ao[1] = bf2f((unsigned short)(w0 >> 16)) * inv;
            ao[2] = bf2f((unsigned short)(w1 & 0xffff)) * inv;
            ao[3] = bf2f((unsigned short)(w1 >> 16)) * inv;
            *(f32x4*)(arow + kt * 16) = ao;

            const unsigned short* vk = vb + kt * 16;
            bf16x4 vf0 = *(const bf16x4*)(vk);
            bf16x4 vf1 = *(const bf16x4*)(vk + 16 * LK);
            bf16x4 vf2 = *(const bf16x4*)(vk + 32 * LK);
            bf16x4 vf3 = *(const bf16x4*)(vk + 48 * LK);
            pacc0 = pv_mfma(eu.v, vf0, pacc0);
            pacc1 = pv_mfma(eu.v, vf1, pacc1);
            pacc2 = pv_mfma(eu.v, vf2, pacc2);
            pacc3 = pv_mfma(eu.v, vf3, pacc3);
        }
    }

    // ---- cross-wave PV reduce + out write ----
    if (wave != 0) {
        #pragma unroll
        for (int j = 0; j < 4; ++j) {
            int r = lg * 4 + j;
            pp[wave - 1][0][r][lr] = pacc0[j];
            pp[wave - 1][1][r][lr] = pacc1[j];
            pp[wave - 1][2][r][lr] = pacc2[j];
            pp[wave - 1][3][r][lr] = pacc3[j];
        }
    }
    __syncthreads();
    if (wave == 0) {
        #pragma unroll
        for (int j = 0; j < 4; ++j) {
            int r = lg * 4 + j;
            float den = den_part[0][r] + den_part[1][r] + den_part[2][r] +
                        den_part[3][r] + 1e-6f;
            float id = 1.0f / den;
            float v0 = pacc0[j] + pp[0][0][r][lr] + pp[1][0][r][lr] + pp[2][0][r][lr];
            float v1 = pacc1[j] + pp[0][1][r][lr] + pp[1][1][r][lr] + pp[2][1][r][lr];
            float v2 = pacc2[j] + pp[0][2][r][lr] + pp[1][2][r][lr] + pp[2][2][r][lr];
            float v3 = pacc3[j] + pp[0][3][r][lr] + pp[1][3][r][lr] + pp[2][3][r][lr];
            float* op = out + ((int64_t)(b * LQ + q0 + r)) * DH + lr;
            op[0]  = v0 * id;
            op[16] = v1 * id;
            op[32] = v2 * id;
            op[48] = v3 * id;
        }
    }
}

extern "C" void kernel_launch(void* const* d_in, const int* in_sizes, int n_in,
                              void* d_out, int out_size, void* d_ws, size_t ws_size,
                              hipStream_t stream) {
    const float* q    = (const float*)d_in[0];
    const float* k    = (const float*)d_in[1];
    const float* v    = (const float*)d_in[2];
    const float* mask = (const float*)d_in[3];
    float* out  = (float*)d_out;
    float* attn = out + (int64_t)NB * LQ * DH;

    unsigned short* qb  = (unsigned short*)d_ws;
    unsigned short* kb  = qb + (int64_t)NB * LQ * DH;
    unsigned short* vtb = kb + (int64_t)NB * LK * DH;

    convert_kernel<<<2560, 256, 0, stream>>>(q, k, v, qb, kb, vtb);
    attn_kernel<<<2048, 256, 0, stream>>>(qb, kb, vtb, mask, out, attn);
}

// Round 10
// 320.287 us; speedup vs baseline: 1.1658x; 1.1658x over previous
//
#include <hip/hip_runtime.h>
#include <stdint.h>

#define NB 16
#define LQ 2048
#define LK 2048
#define DH 64
#define QT 16
#define NW 16                 // waves per block
#define STRIP (NW * 16)       // 256 keys per iteration
#define NIT (LK / STRIP)      // 8

typedef short bf16x8 __attribute__((ext_vector_type(8)));
typedef float f32x4 __attribute__((ext_vector_type(4)));

__device__ __forceinline__ unsigned short f2bf(float f) {
    union { float f; uint32_t u; } v; v.f = f;
    uint32_t u = v.u;
    u += 0x7FFFu + ((u >> 16) & 1u);   // RNE; inputs finite/bounded
    return (unsigned short)(u >> 16);
}
__device__ __forceinline__ float bf2f(unsigned short h) {
    union { uint32_t u; float f; } v; v.u = ((uint32_t)h) << 16;
    return v.f;
}
__device__ __forceinline__ uint32_t pack2(float lo, float hi) {
    return (uint32_t)f2bf(lo) | ((uint32_t)f2bf(hi) << 16);
}

// ---------------- pre-pass: f32 -> bf16 (Q, K) and f32 -> bf16 transposed (V) ----
__global__ void convert_kernel(const float* __restrict__ q, const float* __restrict__ k,
                               const float* __restrict__ v,
                               unsigned short* __restrict__ qb,
                               unsigned short* __restrict__ kb,
                               unsigned short* __restrict__ vtb) {
    int bid = blockIdx.x;
    int tid = threadIdx.x;
    if (bid < 2048) {
        const float* src = (bid < 1024) ? q : k;
        unsigned short* dst = (bid < 1024) ? qb : kb;
        int64_t off = (int64_t)(bid & 1023) * 2048 + (int64_t)tid * 8;
        float4 a = *(const float4*)(src + off);
        float4 b4 = *(const float4*)(src + off + 4);
        uint4 o;
        o.x = pack2(a.x, a.y);
        o.y = pack2(a.z, a.w);
        o.z = pack2(b4.x, b4.y);
        o.w = pack2(b4.z, b4.w);
        *(uint4*)(dst + off) = o;
    } else {
        __shared__ unsigned short tile[64][72];
        int bid2 = bid - 2048;
        int bb = bid2 >> 5, kt = bid2 & 31;
        int k0 = kt * 64;
        int krow = tid >> 2, dc = (tid & 3) * 16;
        const float* vp = v + ((int64_t)(bb * LK) + k0 + krow) * DH + dc;
        float4 x0 = *(const float4*)(vp);
        float4 x1 = *(const float4*)(vp + 4);
        float4 x2 = *(const float4*)(vp + 8);
        float4 x3 = *(const float4*)(vp + 12);
        float vals[16] = {x0.x, x0.y, x0.z, x0.w, x1.x, x1.y, x1.z, x1.w,
                          x2.x, x2.y, x2.z, x2.w, x3.x, x3.y, x3.z, x3.w};
        #pragma unroll
        for (int i = 0; i < 16; ++i) tile[dc + i][krow] = f2bf(vals[i]);
        __syncthreads();
        int d = tid >> 2, kc = (tid & 3) * 16;
        uint4 r0 = *(const uint4*)&tile[d][kc];
        uint4 r1 = *(const uint4*)&tile[d][kc + 8];
        unsigned short* op = vtb + ((int64_t)(bb * DH) + d) * LK + k0 + kc;
        *(uint4*)op = r0;
        *(uint4*)(op + 8) = r1;
    }
}

// asm load helpers (volatile asms keep their mutual order)
__device__ __forceinline__ void ld_f32x4(f32x4& d, const float* p) {
    asm volatile("global_load_dwordx4 %0, %1, off" : "=v"(d) : "v"((uint64_t)p));
}
__device__ __forceinline__ void ld_bf16x8(bf16x8& d, const unsigned short* p) {
    asm volatile("global_load_dwordx4 %0, %1, off" : "=v"(d) : "v"((uint64_t)p));
}
__device__ __forceinline__ void ld_u16(uint32_t& d, const unsigned char* p) {
    asm volatile("global_load_ushort %0, %1, off" : "=v"(d) : "v"((uint64_t)p));
}

// ---------------- pass A: den + mask-nibble cache --------------------------------
// grid 2048 (16 b x 128 q-tiles), 1024 threads (16 waves). Pure read stream:
// mask f32 (HBM) + K (L2) -> MFMA -> e -> den; writes 33.5 MB nibbles + den.
__launch_bounds__(1024, 8)
__global__ void den_kernel(const unsigned short* __restrict__ qb,
                           const unsigned short* __restrict__ kb,
                           const float* __restrict__ mask,
                           unsigned char* __restrict__ maskn,
                           float* __restrict__ den_g) {
    __shared__ float denp[NW][16];

    int bid = blockIdx.x;
    int swz = (bid & 7) * 256 + (bid >> 3);
    int b = swz >> 7;
    int q0 = (swz & 127) * QT;

    int tid = threadIdx.x;
    int lane = tid & 63;
    int wave = tid >> 6;
    int lr = lane & 15, lg = lane >> 4;

    bf16x8 qf0, qf1;
    {
        const unsigned short* qp = qb + ((int64_t)(b * LQ + q0 + lr)) * DH + 8 * lg;
        qf0 = *(const bf16x8*)qp;
        qf1 = *(const bf16x8*)(qp + 32);
    }

    const unsigned short* kpw =
        kb + (int64_t)b * LK * DH + (wave * 16 + lr) * DH + 8 * lg;
    const float* mrow =
        mask + ((int64_t)(b * LQ + q0 + lr)) * LK + wave * 16 + lg * 4;
    unsigned char* nrow =
        maskn + ((int64_t)(b * LQ + q0 + lr)) * (LK / 2) + wave * 8 + lg * 2;

    float dsum = 0.f;
    {
        f32x4  mk[3];
        bf16x8 ka[3], kb_[3];
        #pragma unroll
        for (int t = 0; t < 3; ++t) {
            ld_f32x4(mk[t], mrow + t * STRIP);
            ld_bf16x8(ka[t],  kpw + (int64_t)t * STRIP * DH);
            ld_bf16x8(kb_[t], kpw + (int64_t)t * STRIP * DH + 32);
        }
        #pragma unroll
        for (int kt = 0; kt < NIT; ++kt) {
            int s = kt % 3;
            if (kt < NIT - 2)
                asm volatile("s_waitcnt vmcnt(6)"
                             : "+v"(mk[s]), "+v"(ka[s]), "+v"(kb_[s]));
            else if (kt == NIT - 2)
                asm volatile("s_waitcnt vmcnt(3)"
                             : "+v"(mk[s]), "+v"(ka[s]), "+v"(kb_[s]));
            else
                asm volatile("s_waitcnt vmcnt(0)"
                             : "+v"(mk[s]), "+v"(ka[s]), "+v"(kb_[s]));
            __builtin_amdgcn_sched_barrier(0);

            f32x4 acc = {0.f, 0.f, 0.f, 0.f};
            acc = __builtin_amdgcn_mfma_f32_16x16x32_bf16(ka[s],  qf0, acc, 0, 0, 0);
            acc = __builtin_amdgcn_mfma_f32_16x16x32_bf16(kb_[s], qf1, acc, 0, 0, 0);
            uint32_t nib = 0;
            #pragma unroll
            for (int j = 0; j < 4; ++j) {
                float sc = acc[j] * 0.125f;
                sc = fminf(fmaxf(sc, -15.0f), 15.0f);
                unsigned short p = f2bf(__expf(sc));
                bool mz = (mk[s][j] != 0.f);
                unsigned short eb = mz ? p : (unsigned short)0;
                dsum += bf2f(eb);
                nib |= (mz ? 1u : 0u) << (4 * j);
            }
            *(unsigned short*)(nrow + kt * 128) = (unsigned short)nib;

            if (kt < NIT - 3) {
                ld_f32x4(mk[s], mrow + (kt + 3) * STRIP);
                ld_bf16x8(ka[s],  kpw + (int64_t)(kt + 3) * STRIP * DH);
                ld_bf16x8(kb_[s], kpw + (int64_t)(kt + 3) * STRIP * DH + 32);
            }
        }
    }
    dsum += __shfl_xor(dsum, 16);
    dsum += __shfl_xor(dsum, 32);
    if (lane < 16) denp[wave][lane] = dsum;
    __syncthreads();
    if (wave == 0 && lane < 16) {
        float d = 1e-6f;
        #pragma unroll
        for (int w = 0; w < NW; ++w) d += denp[w][lane];
        den_g[(int64_t)b * LQ + q0 + lane] = d;
    }
}

// ---------------- pass B: attn write (streaming, den known) + PV -----------------
// Recomputes S^T from L2-resident K/Q, reads L3-hot nibbles, stores attn f32
// immediately per strip (no den barrier), then PV from e-LDS.
__launch_bounds__(1024, 8)
__global__ void attn_pv_kernel(const unsigned short* __restrict__ qb,
                               const unsigned short* __restrict__ kb,
                               const unsigned short* __restrict__ vtb,
                               const unsigned char* __restrict__ maskn,
                               const float* __restrict__ den_g,
                               float* __restrict__ out, float* __restrict__ attn) {
    extern __shared__ char smem[];
    float* pp = (float*)(smem + QT * LK * 2);   // [12][16][16]

    int bid = blockIdx.x;
    int swz = (bid & 7) * 256 + (bid >> 3);
    int b = swz >> 7;
    int q0 = (swz & 127) * QT;

    int tid = threadIdx.x;
    int lane = tid & 63;
    int wave = tid >> 6;
    int lr = lane & 15, lg = lane >> 4;

    bf16x8 qf0, qf1;
    {
        const unsigned short* qp = qb + ((int64_t)(b * LQ + q0 + lr)) * DH + 8 * lg;
        qf0 = *(const bf16x8*)qp;
        qf1 = *(const bf16x8*)(qp + 32);
    }
    float inv_lr = 1.0f / den_g[(int64_t)b * LQ + q0 + lr];

    const unsigned short* kpw =
        kb + (int64_t)b * LK * DH + (wave * 16 + lr) * DH + 8 * lg;
    const unsigned char* nrow =
        maskn + ((int64_t)(b * LQ + q0 + lr)) * (LK / 2) + wave * 8 + lg * 2;
    float* arow = attn + ((int64_t)(b * LQ + q0 + lr)) * LK + wave * 16 + lg * 4;

    {
        uint32_t mbk[3];
        bf16x8 ka[3], kb_[3];
        #pragma unroll
        for (int t = 0; t < 3; ++t) {
            ld_u16(mbk[t], nrow + t * 128);
            ld_bf16x8(ka[t],  kpw + (int64_t)t * STRIP * DH);
            ld_bf16x8(kb_[t], kpw + (int64_t)t * STRIP * DH + 32);
        }
        #pragma unroll
        for (int kt = 0; kt < NIT; ++kt) {
            int s = kt % 3;
            if (kt < NIT - 2)
                asm volatile("s_waitcnt vmcnt(6)"
                             : "+v"(mbk[s]), "+v"(ka[s]), "+v"(kb_[s]));
            else if (kt == NIT - 2)
                asm volatile("s_waitcnt vmcnt(3)"
                             : "+v"(mbk[s]), "+v"(ka[s]), "+v"(kb_[s]));
            else
                asm volatile("s_waitcnt vmcnt(0)"
                             : "+v"(mbk[s]), "+v"(ka[s]), "+v"(kb_[s]));
            __builtin_amdgcn_sched_barrier(0);

            f32x4 acc = {0.f, 0.f, 0.f, 0.f};
            acc = __builtin_amdgcn_mfma_f32_16x16x32_bf16(ka[s],  qf0, acc, 0, 0, 0);
            acc = __builtin_amdgcn_mfma_f32_16x16x32_bf16(kb_[s], qf1, acc, 0, 0, 0);
            unsigned short eb[4];
            f32x4 ao;
            #pragma unroll
            for (int j = 0; j < 4; ++j) {
                float sc = acc[j] * 0.125f;
                sc = fminf(fmaxf(sc, -15.0f), 15.0f);
                unsigned short p = f2bf(__expf(sc));
                eb[j] = ((mbk[s] >> (4 * j)) & 0xFu) ? p : (unsigned short)0;
                ao[j] = bf2f(eb[j]) * inv_lr;
            }
            // streaming attn store (den known up-front: no barrier before writes)
            *(f32x4*)(arow + kt * STRIP) = ao;
            // e -> swizzled LDS tile for the PV phase
            uint2 u;
            u.x = (uint32_t)eb[0] | ((uint32_t)eb[1] << 16);
            u.y = (uint32_t)eb[2] | ((uint32_t)eb[3] << 16);
            int c = kt * STRIP + wave * 16 + lg * 4;
            int byteoff = (lr * 4096 + c * 2) ^ ((lr & 7) << 4);
            *(uint2*)(smem + byteoff) = u;

            if (kt < NIT - 3) {
                ld_u16(mbk[s], nrow + (kt + 3) * 128);
                ld_bf16x8(ka[s],  kpw + (int64_t)(kt + 3) * STRIP * DH);
                ld_bf16x8(kb_[s], kpw + (int64_t)(kt + 3) * STRIP * DH + 32);
            }
        }
    }
    __syncthreads();

    // ---- PV: wave w -> col-tile (w&3)*16, K-quarter w>>2 ----
    f32x4 pacc = {0.f, 0.f, 0.f, 0.f};
    int cw = (wave & 3) * 16, kq = wave >> 2;
    {
        const unsigned short* vp =
            vtb + ((int64_t)(b * DH + cw + lr)) * LK + kq * 512 + 8 * lg;
        int rowbase = lr * 4096;
        int sw = (lr & 7) << 4;
        int kk0 = kq * 512;
        #pragma unroll 4
        for (int kk = 0; kk < 512; kk += 32) {
            int byteoff = (rowbase + (kk0 + kk + 8 * lg) * 2) ^ sw;
            bf16x8 ef = *(const bf16x8*)(smem + byteoff);
            bf16x8 vf = *(const bf16x8*)(vp + kk);
            pacc = __builtin_amdgcn_mfma_f32_16x16x32_bf16(ef, vf, pacc, 0, 0, 0);
        }
    }
    if (kq != 0) {
        #pragma unroll
        for (int j = 0; j < 4; ++j)
            pp[((kq - 1) * 4 + (wave & 3)) * 256 + (lg * 4 + j) * 16 + lr] = pacc[j];
    }
    __syncthreads();
    if (kq == 0) {
        int c4 = wave & 3;
        #pragma unroll
        for (int j = 0; j < 4; ++j) {
            int r = lg * 4 + j;
            float dd = den_g[(int64_t)b * LQ + q0 + r];
            float val = pacc[j] + pp[(c4) * 256 + r * 16 + lr] +
                        pp[(4 + c4) * 256 + r * 16 + lr] +
                        pp[(8 + c4) * 256 + r * 16 + lr];
            out[((int64_t)(b * LQ + q0 + r)) * DH + cw + lr] = val / dd;
        }
    }
}

extern "C" void kernel_launch(void* const* d_in, const int* in_sizes, int n_in,
                              void* d_out, int out_size, void* d_ws, size_t ws_size,
                              hipStream_t stream) {
    const float* q    = (const float*)d_in[0];
    const float* k    = (const float*)d_in[1];
    const float* v    = (const float*)d_in[2];
    const float* mask = (const float*)d_in[3];
    float* out  = (float*)d_out;
    float* attn = out + (int64_t)NB * LQ * DH;

    unsigned short* qb  = (unsigned short*)d_ws;
    unsigned short* kb  = qb + (int64_t)NB * LQ * DH;
    unsigned short* vtb = kb + (int64_t)NB * LK * DH;
    unsigned char*  maskn = (unsigned char*)(vtb + (int64_t)NB * DH * LK);
    float* den_g = (float*)(maskn + (int64_t)NB * LQ * (LK / 2));

    (void)hipFuncSetAttribute((const void*)attn_pv_kernel,
                              hipFuncAttributeMaxDynamicSharedMemorySize, 77824);

    convert_kernel<<<2560, 256, 0, stream>>>(q, k, v, qb, kb, vtb);
    den_kernel<<<2048, 1024, 0, stream>>>(qb, kb, mask, maskn, den_g);
    attn_pv_kernel<<<2048, 1024, 77824, stream>>>(qb, kb, vtb, maskn, den_g,
                                                  out, attn);
}

// Round 11
// 315.259 us; speedup vs baseline: 1.1844x; 1.0159x over previous
//
#include <hip/hip_runtime.h>
#include <stdint.h>

#define NB 16
#define LQ 2048
#define LK 2048
#define DH 64
#define QT 16
#define NW 16                 // waves per block
#define STRIP (NW * 16)       // 256 keys per iteration
#define NIT (LK / STRIP)      // 8

typedef short bf16x8 __attribute__((ext_vector_type(8)));
typedef float f32x4 __attribute__((ext_vector_type(4)));

__device__ __forceinline__ unsigned short f2bf(float f) {
    union { float f; uint32_t u; } v; v.f = f;
    uint32_t u = v.u;
    u += 0x7FFFu + ((u >> 16) & 1u);   // RNE; inputs finite/bounded
    return (unsigned short)(u >> 16);
}
__device__ __forceinline__ float bf2f(unsigned short h) {
    union { uint32_t u; float f; } v; v.u = ((uint32_t)h) << 16;
    return v.f;
}
__device__ __forceinline__ uint32_t pack2(float lo, float hi) {
    return (uint32_t)f2bf(lo) | ((uint32_t)f2bf(hi) << 16);
}

// ---------------- pre-pass: f32 -> bf16 (Q, K) and f32 -> bf16 transposed (V) ----
__global__ void convert_kernel(const float* __restrict__ q, const float* __restrict__ k,
                               const float* __restrict__ v,
                               unsigned short* __restrict__ qb,
                               unsigned short* __restrict__ kb,
                               unsigned short* __restrict__ vtb) {
    int bid = blockIdx.x;
    int tid = threadIdx.x;
    if (bid < 2048) {
        const float* src = (bid < 1024) ? q : k;
        unsigned short* dst = (bid < 1024) ? qb : kb;
        int64_t off = (int64_t)(bid & 1023) * 2048 + (int64_t)tid * 8;
        float4 a = *(const float4*)(src + off);
        float4 b4 = *(const float4*)(src + off + 4);
        uint4 o;
        o.x = pack2(a.x, a.y);
        o.y = pack2(a.z, a.w);
        o.z = pack2(b4.x, b4.y);
        o.w = pack2(b4.z, b4.w);
        *(uint4*)(dst + off) = o;
    } else {
        __shared__ unsigned short tile[64][72];
        int bid2 = bid - 2048;
        int bb = bid2 >> 5, kt = bid2 & 31;
        int k0 = kt * 64;
        int krow = tid >> 2, dc = (tid & 3) * 16;
        const float* vp = v + ((int64_t)(bb * LK) + k0 + krow) * DH + dc;
        float4 x0 = *(const float4*)(vp);
        float4 x1 = *(const float4*)(vp + 4);
        float4 x2 = *(const float4*)(vp + 8);
        float4 x3 = *(const float4*)(vp + 12);
        float vals[16] = {x0.x, x0.y, x0.z, x0.w, x1.x, x1.y, x1.z, x1.w,
                          x2.x, x2.y, x2.z, x2.w, x3.x, x3.y, x3.z, x3.w};
        #pragma unroll
        for (int i = 0; i < 16; ++i) tile[dc + i][krow] = f2bf(vals[i]);
        __syncthreads();
        int d = tid >> 2, kc = (tid & 3) * 16;
        uint4 r0 = *(const uint4*)&tile[d][kc];
        uint4 r1 = *(const uint4*)&tile[d][kc + 8];
        unsigned short* op = vtb + ((int64_t)(bb * DH) + d) * LK + k0 + kc;
        *(uint4*)op = r0;
        *(uint4*)(op + 8) = r1;
    }
}

// asm load helpers (volatile asms keep their mutual order)
__device__ __forceinline__ void ld_bf16x8(bf16x8& d, const unsigned short* p) {
    asm volatile("global_load_dwordx4 %0, %1, off" : "=v"(d) : "v"((uint64_t)p));
}
__device__ __forceinline__ void ld_u16(uint32_t& d, const unsigned char* p) {
    asm volatile("global_load_ushort %0, %1, off" : "=v"(d) : "v"((uint64_t)p));
}

// ---------------- pass A: den + mask-nibble cache --------------------------------
// phase 1: unmasked p -> LDS (pure L2 compute, no HBM).
// phase 2: wave w = row w; CONTIGUOUS mask read (1KB/instr), select vs LDS p,
//          CONTIGUOUS nibble write, in-wave den reduce.
__launch_bounds__(1024, 8)
__global__ void den_kernel(const unsigned short* __restrict__ qb,
                           const unsigned short* __restrict__ kb,
                           const float* __restrict__ mask,
                           unsigned char* __restrict__ maskn,
                           float* __restrict__ den_g) {
    extern __shared__ char smem[];   // p-tile [16][2048] bf16, XOR-swizzled

    int bid = blockIdx.x;
    int swz = (bid & 7) * 256 + (bid >> 3);
    int b = swz >> 7;
    int q0 = (swz & 127) * QT;

    int tid = threadIdx.x;
    int lane = tid & 63;
    int wave = tid >> 6;
    int lr = lane & 15, lg = lane >> 4;

    bf16x8 qf0, qf1;
    {
        const unsigned short* qp = qb + ((int64_t)(b * LQ + q0 + lr)) * DH + 8 * lg;
        qf0 = *(const bf16x8*)qp;
        qf1 = *(const bf16x8*)(qp + 32);
    }

    // ---- phase 1: p = exp(clamp(QK^T/8)) (unmasked) -> LDS ----
    {
        const unsigned short* kpw =
            kb + (int64_t)b * LK * DH + (wave * 16 + lr) * DH + 8 * lg;
        bf16x8 kf0 = *(const bf16x8*)kpw;
        bf16x8 kf1 = *(const bf16x8*)(kpw + 32);
        #pragma unroll
        for (int kt = 0; kt < NIT; ++kt) {
            bf16x8 nk0, nk1;
            if (kt + 1 < NIT) {
                const unsigned short* np = kpw + (int64_t)(kt + 1) * STRIP * DH;
                nk0 = *(const bf16x8*)np;
                nk1 = *(const bf16x8*)(np + 32);
            }
            f32x4 acc = {0.f, 0.f, 0.f, 0.f};
            acc = __builtin_amdgcn_mfma_f32_16x16x32_bf16(kf0, qf0, acc, 0, 0, 0);
            acc = __builtin_amdgcn_mfma_f32_16x16x32_bf16(kf1, qf1, acc, 0, 0, 0);
            unsigned short eb[4];
            #pragma unroll
            for (int j = 0; j < 4; ++j) {
                float sc = acc[j] * 0.125f;
                sc = fminf(fmaxf(sc, -15.0f), 15.0f);
                eb[j] = f2bf(__expf(sc));
            }
            uint2 u;
            u.x = (uint32_t)eb[0] | ((uint32_t)eb[1] << 16);
            u.y = (uint32_t)eb[2] | ((uint32_t)eb[3] << 16);
            int c = kt * STRIP + wave * 16 + lg * 4;
            int byteoff = (lr * 4096 + c * 2) ^ ((lr & 7) << 4);
            *(uint2*)(smem + byteoff) = u;
            kf0 = nk0; kf1 = nk1;
        }
    }
    __syncthreads();

    // ---- phase 2: contiguous mask stream; nibbles + den ----
    {
        int r = wave;
        const float* mrow = mask + ((int64_t)(b * LQ + q0 + r)) * LK;
        uint32_t* nrow = (uint32_t*)(maskn + ((int64_t)(b * LQ + q0 + r)) * (LK / 2));
        int c0l = lane * 8;
        f32x4 mk[8];
        #pragma unroll
        for (int i = 0; i < 4; ++i) {           // all 8 loads issued up-front
            mk[2 * i]     = *(const f32x4*)(mrow + i * 512 + c0l);
            mk[2 * i + 1] = *(const f32x4*)(mrow + i * 512 + c0l + 4);
        }
        float dsum = 0.f;
        int rowbase = r * 4096, sw = (r & 7) << 4;
        #pragma unroll
        for (int i = 0; i < 4; ++i) {
            int byteoff = (rowbase + (i * 512 + c0l) * 2) ^ sw;
            bf16x8 pv = *(const bf16x8*)(smem + byteoff);
            uint32_t nib = 0;
            #pragma unroll
            for (int j = 0; j < 8; ++j) {
                float m = (j < 4) ? mk[2 * i][j] : mk[2 * i + 1][j - 4];
                bool mz = (m != 0.f);
                if (mz) dsum += bf2f((unsigned short)pv[j]);
                nib |= (mz ? 1u : 0u) << (4 * j);
            }
            nrow[i * 64 + lane] = nib;          // contiguous 256B per instr
        }
        dsum += __shfl_xor(dsum, 1);
        dsum += __shfl_xor(dsum, 2);
        dsum += __shfl_xor(dsum, 4);
        dsum += __shfl_xor(dsum, 8);
        dsum += __shfl_xor(dsum, 16);
        dsum += __shfl_xor(dsum, 32);
        if (lane == 0) den_g[(int64_t)b * LQ + q0 + r] = dsum + 1e-6f;
    }
}

// ---------------- pass B: e-tile rebuild + PV + CONTIGUOUS attn write ------------
__launch_bounds__(1024, 8)
__global__ void attn_pv_kernel(const unsigned short* __restrict__ qb,
                               const unsigned short* __restrict__ kb,
                               const unsigned short* __restrict__ vtb,
                               const unsigned char* __restrict__ maskn,
                               const float* __restrict__ den_g,
                               float* __restrict__ out, float* __restrict__ attn) {
    extern __shared__ char smem[];
    float* pp = (float*)(smem + QT * LK * 2);   // [12][16][16]

    int bid = blockIdx.x;
    int swz = (bid & 7) * 256 + (bid >> 3);
    int b = swz >> 7;
    int q0 = (swz & 127) * QT;

    int tid = threadIdx.x;
    int lane = tid & 63;
    int wave = tid >> 6;
    int lr = lane & 15, lg = lane >> 4;

    bf16x8 qf0, qf1;
    {
        const unsigned short* qp = qb + ((int64_t)(b * LQ + q0 + lr)) * DH + 8 * lg;
        qf0 = *(const bf16x8*)qp;
        qf1 = *(const bf16x8*)(qp + 32);
    }

    const unsigned short* kpw =
        kb + (int64_t)b * LK * DH + (wave * 16 + lr) * DH + 8 * lg;
    const unsigned char* nrow =
        maskn + ((int64_t)(b * LQ + q0 + lr)) * (LK / 2) + wave * 8 + lg * 2;

    // ---- phase 1: masked e -> LDS (nibbles: tiny L3-hot reads; K in L2) ----
    {
        uint32_t mbk[3];
        bf16x8 ka[3], kb_[3];
        #pragma unroll
        for (int t = 0; t < 3; ++t) {
            ld_u16(mbk[t], nrow + t * 128);
            ld_bf16x8(ka[t],  kpw + (int64_t)t * STRIP * DH);
            ld_bf16x8(kb_[t], kpw + (int64_t)t * STRIP * DH + 32);
        }
        #pragma unroll
        for (int kt = 0; kt < NIT; ++kt) {
            int s = kt % 3;
            if (kt < NIT - 2)
                asm volatile("s_waitcnt vmcnt(6)"
                             : "+v"(mbk[s]), "+v"(ka[s]), "+v"(kb_[s]));
            else if (kt == NIT - 2)
                asm volatile("s_waitcnt vmcnt(3)"
                             : "+v"(mbk[s]), "+v"(ka[s]), "+v"(kb_[s]));
            else
                asm volatile("s_waitcnt vmcnt(0)"
                             : "+v"(mbk[s]), "+v"(ka[s]), "+v"(kb_[s]));
            __builtin_amdgcn_sched_barrier(0);

            f32x4 acc = {0.f, 0.f, 0.f, 0.f};
            acc = __builtin_amdgcn_mfma_f32_16x16x32_bf16(ka[s],  qf0, acc, 0, 0, 0);
            acc = __builtin_amdgcn_mfma_f32_16x16x32_bf16(kb_[s], qf1, acc, 0, 0, 0);
            unsigned short eb[4];
            #pragma unroll
            for (int j = 0; j < 4; ++j) {
                float sc = acc[j] * 0.125f;
                sc = fminf(fmaxf(sc, -15.0f), 15.0f);
                unsigned short p = f2bf(__expf(sc));
                eb[j] = ((mbk[s] >> (4 * j)) & 0xFu) ? p : (unsigned short)0;
            }
            uint2 u;
            u.x = (uint32_t)eb[0] | ((uint32_t)eb[1] << 16);
            u.y = (uint32_t)eb[2] | ((uint32_t)eb[3] << 16);
            int c = kt * STRIP + wave * 16 + lg * 4;
            int byteoff = (lr * 4096 + c * 2) ^ ((lr & 7) << 4);
            *(uint2*)(smem + byteoff) = u;

            if (kt < NIT - 3) {
                ld_u16(mbk[s], nrow + (kt + 3) * 128);
                ld_bf16x8(ka[s],  kpw + (int64_t)(kt + 3) * STRIP * DH);
                ld_bf16x8(kb_[s], kpw + (int64_t)(kt + 3) * STRIP * DH + 32);
            }
        }
    }
    __syncthreads();

    // ---- PV: wave w -> col-tile (w&3)*16, K-quarter w>>2 ----
    f32x4 pacc = {0.f, 0.f, 0.f, 0.f};
    int cw = (wave & 3) * 16, kq = wave >> 2;
    {
        const unsigned short* vp =
            vtb + ((int64_t)(b * DH + cw + lr)) * LK + kq * 512 + 8 * lg;
        int rowbase = lr * 4096;
        int sw = (lr & 7) << 4;
        int kk0 = kq * 512;
        #pragma unroll 4
        for (int kk = 0; kk < 512; kk += 32) {
            int byteoff = (rowbase + (kk0 + kk + 8 * lg) * 2) ^ sw;
            bf16x8 ef = *(const bf16x8*)(smem + byteoff);
            bf16x8 vf = *(const bf16x8*)(vp + kk);
            pacc = __builtin_amdgcn_mfma_f32_16x16x32_bf16(ef, vf, pacc, 0, 0, 0);
        }
    }
    if (kq != 0) {
        #pragma unroll
        for (int j = 0; j < 4; ++j)
            pp[((kq - 1) * 4 + (wave & 3)) * 256 + (lg * 4 + j) * 16 + lr] = pacc[j];
    }
    __syncthreads();
    if (kq == 0) {
        int c4 = wave & 3;
        #pragma unroll
        for (int j = 0; j < 4; ++j) {
            int r = lg * 4 + j;
            float dd = den_g[(int64_t)b * LQ + q0 + r];
            float val = pacc[j] + pp[(c4) * 256 + r * 16 + lr] +
                        pp[(4 + c4) * 256 + r * 16 + lr] +
                        pp[(8 + c4) * 256 + r * 16 + lr];
            out[((int64_t)(b * LQ + q0 + r)) * DH + cw + lr] = val / dd;
        }
    }

    // ---- attn write LAST: contiguous 1KB bursts from LDS, nothing waits on it ----
    {
        int r = wave;
        float inv = 1.0f / den_g[(int64_t)b * LQ + q0 + r];
        float* ap = attn + ((int64_t)(b * LQ + q0 + r)) * LK;
        int rowbase = r * 4096;
        int sw = (r & 7) << 4;
        int c0l = lane * 8;
        #pragma unroll
        for (int i = 0; i < 4; ++i) {
            int byteoff = (rowbase + (i * 512 + c0l) * 2) ^ sw;
            bf16x8 ev = *(const bf16x8*)(smem + byteoff);
            f32x4 o0, o1;
            o0[0] = bf2f((unsigned short)ev[0]) * inv;
            o0[1] = bf2f((unsigned short)ev[1]) * inv;
            o0[2] = bf2f((unsigned short)ev[2]) * inv;
            o0[3] = bf2f((unsigned short)ev[3]) * inv;
            o1[0] = bf2f((unsigned short)ev[4]) * inv;
            o1[1] = bf2f((unsigned short)ev[5]) * inv;
            o1[2] = bf2f((unsigned short)ev[6]) * inv;
            o1[3] = bf2f((unsigned short)ev[7]) * inv;
            *(f32x4*)(ap + i * 512 + c0l) = o0;
            *(f32x4*)(ap + i * 512 + c0l + 4) = o1;
        }
    }
}

extern "C" void kernel_launch(void* const* d_in, const int* in_sizes, int n_in,
                              void* d_out, int out_size, void* d_ws, size_t ws_size,
                              hipStream_t stream) {
    const float* q    = (const float*)d_in[0];
    const float* k    = (const float*)d_in[1];
    const float* v    = (const float*)d_in[2];
    const float* mask = (const float*)d_in[3];
    float* out  = (float*)d_out;
    float* attn = out + (int64_t)NB * LQ * DH;

    unsigned short* qb  = (unsigned short*)d_ws;
    unsigned short* kb  = qb + (int64_t)NB * LQ * DH;
    unsigned short* vtb = kb + (int64_t)NB * LK * DH;
    unsigned char*  maskn = (unsigned char*)(vtb + (int64_t)NB * DH * LK);
    float* den_g = (float*)(maskn + (int64_t)NB * LQ * (LK / 2));

    (void)hipFuncSetAttribute((const void*)den_kernel,
                              hipFuncAttributeMaxDynamicSharedMemorySize, 65536);
    (void)hipFuncSetAttribute((const void*)attn_pv_kernel,
                              hipFuncAttributeMaxDynamicSharedMemorySize, 77824);

    convert_kernel<<<2560, 256, 0, stream>>>(q, k, v, qb, kb, vtb);
    den_kernel<<<2048, 1024, 65536, stream>>>(qb, kb, mask, maskn, den_g);
    attn_pv_kernel<<<2048, 1024, 77824, stream>>>(qb, kb, vtb, maskn, den_g,
                                                  out, attn);
}

// Round 12
// 233.440 us; speedup vs baseline: 1.5995x; 1.3505x over previous
//
#include <hip/hip_runtime.h>
#include <stdint.h>

#define NB 16
#define LQ 2048
#define LK 2048
#define DH 64
#define QT 16
#define NW 16
#define STRIP 256            // NW*16 keys per ph1 iteration
#define NIT 8                // LK/STRIP
#define TPB 8                // q-tiles per block

typedef short bf16x8 __attribute__((ext_vector_type(8)));
typedef float f32x4 __attribute__((ext_vector_type(4)));

__device__ __forceinline__ unsigned short f2bf(float f) {
    union { float f; uint32_t u; } v; v.f = f;
    uint32_t u = v.u;
    u += 0x7FFFu + ((u >> 16) & 1u);
    return (unsigned short)(u >> 16);
}
__device__ __forceinline__ float bf2f(unsigned short h) {
    union { uint32_t u; float f; } v; v.u = ((uint32_t)h) << 16;
    return v.f;
}
__device__ __forceinline__ uint32_t pack2(float lo, float hi) {
    return (uint32_t)f2bf(lo) | ((uint32_t)f2bf(hi) << 16);
}

// ---------------- pre-pass: f32 -> bf16 (Q, K) and f32 -> bf16 transposed (V) ----
__global__ void convert_kernel(const float* __restrict__ q, const float* __restrict__ k,
                               const float* __restrict__ v,
                               unsigned short* __restrict__ qb,
                               unsigned short* __restrict__ kb,
                               unsigned short* __restrict__ vtb) {
    int bid = blockIdx.x;
    int tid = threadIdx.x;
    if (bid < 2048) {
        const float* src = (bid < 1024) ? q : k;
        unsigned short* dst = (bid < 1024) ? qb : kb;
        int64_t off = (int64_t)(bid & 1023) * 2048 + (int64_t)tid * 8;
        float4 a = *(const float4*)(src + off);
        float4 b4 = *(const float4*)(src + off + 4);
        uint4 o;
        o.x = pack2(a.x, a.y);
        o.y = pack2(a.z, a.w);
        o.z = pack2(b4.x, b4.y);
        o.w = pack2(b4.z, b4.w);
        *(uint4*)(dst + off) = o;
    } else {
        __shared__ unsigned short tile[64][72];
        int bid2 = bid - 2048;
        int bb = bid2 >> 5, kt = bid2 & 31;
        int k0 = kt * 64;
        int krow = tid >> 2, dc = (tid & 3) * 16;
        const float* vp = v + ((int64_t)(bb * LK) + k0 + krow) * DH + dc;
        float4 x0 = *(const float4*)(vp);
        float4 x1 = *(const float4*)(vp + 4);
        float4 x2 = *(const float4*)(vp + 8);
        float4 x3 = *(const float4*)(vp + 12);
        float vals[16] = {x0.x, x0.y, x0.z, x0.w, x1.x, x1.y, x1.z, x1.w,
                          x2.x, x2.y, x2.z, x2.w, x3.x, x3.y, x3.z, x3.w};
        #pragma unroll
        for (int i = 0; i < 16; ++i) tile[dc + i][krow] = f2bf(vals[i]);
        __syncthreads();
        int d = tid >> 2, kc = (tid & 3) * 16;
        uint4 r0 = *(const uint4*)&tile[d][kc];
        uint4 r1 = *(const uint4*)&tile[d][kc + 8];
        unsigned short* op = vtb + ((int64_t)(bb * DH) + d) * LK + k0 + kc;
        *(uint4*)op = r0;
        *(uint4*)(op + 8) = r1;
    }
}

// ---------------- fused attention: 1 block/CU, 8-tile double-buffered pipeline ----
// grid 256, 1024 threads (16 waves). LDS: e dbuf 2x65536 + den[2][16] 128 +
// pp[12][16][16] 12288 = 143488 B -> exactly 1 block/CU.
// Each block: one batch, 8 consecutive q-tiles. Per iteration every region mixes
// stream work (mask read / attn write) with compute (MFMA/exp/PV).
__launch_bounds__(1024, 4)
__global__ void attn_kernel(const unsigned short* __restrict__ qb,
                            const unsigned short* __restrict__ kb,
                            const unsigned short* __restrict__ vtb,
                            const float* __restrict__ mask,
                            float* __restrict__ out, float* __restrict__ attn) {
    extern __shared__ char smem[];
    float* denb = (float*)(smem + 131072);           // [2][16]
    float* pp   = (float*)(smem + 131072 + 128);     // [12][16][16]

    int bid = blockIdx.x;
    int b  = (bid & 7) * 2 + (bid >> 7);   // 2 batches per XCD -> K/V L2-resident
    int qc = (bid >> 3) & 15;              // q-chunk: 8 tiles

    int tid = threadIdx.x;
    int lane = tid & 63, wave = tid >> 6;
    int lr = lane & 15, lg = lane >> 4;

    const int64_t brow = (int64_t)b * LQ;
    const unsigned short* kpw =
        kb + (int64_t)b * LK * DH + (wave * 16 + lr) * DH + 8 * lg;

    // ---- ph1: unmasked p = exp(clamp(QK^T/8)) -> ebuf (K/Q from L2) ----
    auto ph1 = [&](int q0, char* ebuf) {
        const unsigned short* qp = qb + (brow + q0 + lr) * DH + 8 * lg;
        bf16x8 qf0 = *(const bf16x8*)qp;
        bf16x8 qf1 = *(const bf16x8*)(qp + 32);
        bf16x8 kf0 = *(const bf16x8*)kpw;
        bf16x8 kf1 = *(const bf16x8*)(kpw + 32);
        #pragma unroll
        for (int kt = 0; kt < NIT; ++kt) {
            bf16x8 nk0, nk1;
            if (kt + 1 < NIT) {
                const unsigned short* np = kpw + (int64_t)(kt + 1) * STRIP * DH;
                nk0 = *(const bf16x8*)np;
                nk1 = *(const bf16x8*)(np + 32);
            }
            f32x4 acc = {0.f, 0.f, 0.f, 0.f};
            acc = __builtin_amdgcn_mfma_f32_16x16x32_bf16(kf0, qf0, acc, 0, 0, 0);
            acc = __builtin_amdgcn_mfma_f32_16x16x32_bf16(kf1, qf1, acc, 0, 0, 0);
            unsigned short eb[4];
            #pragma unroll
            for (int j = 0; j < 4; ++j) {
                float sc = acc[j] * 0.125f;
                sc = fminf(fmaxf(sc, -15.0f), 15.0f);
                eb[j] = f2bf(__expf(sc));
            }
            uint2 u;
            u.x = (uint32_t)eb[0] | ((uint32_t)eb[1] << 16);
            u.y = (uint32_t)eb[2] | ((uint32_t)eb[3] << 16);
            int c = kt * STRIP + wave * 16 + lg * 4;
            int byteoff = (lr * 4096 + c * 2) ^ ((lr & 7) << 4);
            *(uint2*)(ebuf + byteoff) = u;
            kf0 = nk0; kf1 = nk1;
        }
    };

    f32x4 mk[8];   // mask stage (wave-per-row, contiguous)

    auto mload = [&](int q0) {
        const float* mrow = mask + (brow + q0 + wave) * LK;
        int c0l = lane * 8;
        #pragma unroll
        for (int i = 0; i < 4; ++i) {
            mk[2 * i]     = *(const f32x4*)(mrow + i * 512 + c0l);
            mk[2 * i + 1] = *(const f32x4*)(mrow + i * 512 + c0l + 4);
        }
    };
    auto mconsume = [&](char* ebuf, int par) {
        int r = wave;
        int rowbase = r * 4096, sw = (r & 7) << 4;
        int c0l = lane * 8;
        float dsum = 0.f;
        #pragma unroll
        for (int i = 0; i < 4; ++i) {
            int byteoff = (rowbase + (i * 512 + c0l) * 2) ^ sw;
            bf16x8 pv = *(const bf16x8*)(ebuf + byteoff);
            uint32_t packed[4];
            #pragma unroll
            for (int h = 0; h < 4; ++h) {
                float m0 = (h < 2) ? mk[2 * i][2 * h] : mk[2 * i + 1][2 * h - 4];
                float m1 = (h < 2) ? mk[2 * i][2 * h + 1] : mk[2 * i + 1][2 * h - 3];
                unsigned short e0 = (m0 != 0.f) ? (unsigned short)pv[2 * h] : (unsigned short)0;
                unsigned short e1 = (m1 != 0.f) ? (unsigned short)pv[2 * h + 1] : (unsigned short)0;
                dsum += bf2f(e0) + bf2f(e1);
                packed[h] = (uint32_t)e0 | ((uint32_t)e1 << 16);
            }
            uint4 wb = {packed[0], packed[1], packed[2], packed[3]};
            int byteoff2 = (rowbase + (i * 512 + c0l) * 2) ^ sw;
            *(uint4*)(ebuf + byteoff2) = wb;
        }
        dsum += __shfl_xor(dsum, 1);
        dsum += __shfl_xor(dsum, 2);
        dsum += __shfl_xor(dsum, 4);
        dsum += __shfl_xor(dsum, 8);
        dsum += __shfl_xor(dsum, 16);
        dsum += __shfl_xor(dsum, 32);
        if (lane == 0) denb[par * 16 + r] = dsum + 1e-6f;
    };

    auto atw = [&](int q0, char* ebuf, int par) {
        int r = wave;
        float inv = 1.0f / denb[par * 16 + r];
        float* ap = attn + (brow + q0 + r) * LK;
        int rowbase = r * 4096, sw = (r & 7) << 4;
        int c0l = lane * 8;
        #pragma unroll
        for (int i = 0; i < 4; ++i) {
            int byteoff = (rowbase + (i * 512 + c0l) * 2) ^ sw;
            bf16x8 ev = *(const bf16x8*)(ebuf + byteoff);
            f32x4 o0, o1;
            o0[0] = bf2f((unsigned short)ev[0]) * inv;
            o0[1] = bf2f((unsigned short)ev[1]) * inv;
            o0[2] = bf2f((unsigned short)ev[2]) * inv;
            o0[3] = bf2f((unsigned short)ev[3]) * inv;
            o1[0] = bf2f((unsigned short)ev[4]) * inv;
            o1[1] = bf2f((unsigned short)ev[5]) * inv;
            o1[2] = bf2f((unsigned short)ev[6]) * inv;
            o1[3] = bf2f((unsigned short)ev[7]) * inv;
            *(f32x4*)(ap + i * 512 + c0l) = o0;
            *(f32x4*)(ap + i * 512 + c0l + 4) = o1;
        }
    };

    char* eb0 = smem;
    char* eb1 = smem + 65536;

    // ---- prologue: tile 0 ----
    {
        int q0 = (qc * TPB) * QT;
        ph1(q0, eb0);
        __syncthreads();
        mload(q0);
        mconsume(eb0, 0);
        __syncthreads();
    }

    // ---- pipelined main loop ----
    for (int i = 0; i < TPB; ++i) {
        int par = i & 1;
        char* ebuf = par ? eb1 : eb0;
        char* nbuf = par ? eb0 : eb1;
        int q0  = (qc * TPB + i) * QT;
        int q0n = (qc * TPB + i + 1) * QT;

        // ===== REGION A: PV(i)+out(i)  ||  ph1(i+1) =====
        f32x4 pacc = {0.f, 0.f, 0.f, 0.f};
        int cw = (wave & 3) * 16, kq = wave >> 2;
        {
            const unsigned short* vp =
                vtb + ((int64_t)(b * DH + cw + lr)) * LK + kq * 512 + 8 * lg;
            int rowbase = lr * 4096;
            int sw = (lr & 7) << 4;
            int kk0 = kq * 512;
            #pragma unroll 4
            for (int kk = 0; kk < 512; kk += 32) {
                int byteoff = (rowbase + (kk0 + kk + 8 * lg) * 2) ^ sw;
                bf16x8 ef = *(const bf16x8*)(ebuf + byteoff);
                bf16x8 vf = *(const bf16x8*)(vp + kk);
                pacc = __builtin_amdgcn_mfma_f32_16x16x32_bf16(ef, vf, pacc, 0, 0, 0);
            }
        }
        if (kq != 0) {
            #pragma unroll
            for (int j = 0; j < 4; ++j)
                pp[((kq - 1) * 4 + (wave & 3)) * 256 + (lg * 4 + j) * 16 + lr] = pacc[j];
        }
        __syncthreads();   // bar A
        if (kq == 0) {
            int c4 = wave & 3;
            #pragma unroll
            for (int j = 0; j < 4; ++j) {
                int r = lg * 4 + j;
                float dd = denb[par * 16 + r];
                float val = pacc[j] + pp[(c4) * 256 + r * 16 + lr] +
                            pp[(4 + c4) * 256 + r * 16 + lr] +
                            pp[(8 + c4) * 256 + r * 16 + lr];
                out[(brow + q0 + r) * DH + cw + lr] = val / dd;
            }
        }
        if (i + 1 < TPB) ph1(q0n, nbuf);
        __syncthreads();   // bar B

        // ===== REGION B: mask-load(i+1) -> attn-write(i) -> select+den(i+1) =====
        if (i + 1 < TPB) mload(q0n);
        atw(q0, ebuf, par);
        if (i + 1 < TPB) mconsume(nbuf, par ^ 1);
        __syncthreads();   // bar C
    }
}

extern "C" void kernel_launch(void* const* d_in, const int* in_sizes, int n_in,
                              void* d_out, int out_size, void* d_ws, size_t ws_size,
                              hipStream_t stream) {
    const float* q    = (const float*)d_in[0];
    const float* k    = (const float*)d_in[1];
    const float* v    = (const float*)d_in[2];
    const float* mask = (const float*)d_in[3];
    float* out  = (float*)d_out;
    float* attn = out + (int64_t)NB * LQ * DH;

    unsigned short* qb  = (unsigned short*)d_ws;
    unsigned short* kb  = qb + (int64_t)NB * LQ * DH;
    unsigned short* vtb = kb + (int64_t)NB * LK * DH;

    (void)hipFuncSetAttribute((const void*)attn_kernel,
                              hipFuncAttributeMaxDynamicSharedMemorySize, 143488);

    convert_kernel<<<2560, 256, 0, stream>>>(q, k, v, qb, kb, vtb);
    attn_kernel<<<256, 1024, 143488, stream>>>(qb, kb, vtb, mask, out, attn);
}